// Round 4
// baseline (720.208 us; speedup 1.0000x reference)
//
#include <hip/hip_runtime.h>
#include <stdint.h>

typedef __bf16 bf16;
typedef bf16 bf16x8 __attribute__((ext_vector_type(8)));
typedef float f32x4 __attribute__((ext_vector_type(4)));

#define B_  4
#define L_  4096
#define DM  1024
#define DS  256
#define DH  4096
#define BL  16384   // B_*L_
#define CL  64      // scan chunk length
#define NC  64      // chunks per sequence

__device__ __forceinline__ float bfbits(uint32_t lo16) {
  union { uint32_t u; float f; } v; v.u = lo16 << 16; return v.f;
}

__device__ __forceinline__ void async16(const bf16* g, bf16* l) {
  __builtin_amdgcn_global_load_lds(
      (const __attribute__((address_space(1))) uint32_t*)g,
      (__attribute__((address_space(3))) uint32_t*)l, 16, 0, 0);
}

// ---------------- Phase A ----------------
__global__ void phaseA(const float* __restrict__ nu_log,
                       const float* __restrict__ th_log,
                       float* __restrict__ scal) {
  int n = threadIdx.x;
  float nu = __expf(nu_log[n]);
  float th = __expf(th_log[n]);
  float mod = __expf(-nu);
  float lr = mod * cosf(th);
  float li = mod * sinf(th);
  float g = sqrtf(fmaxf(1.0f - mod * mod, 0.0f));
  float pr = 1.f, pi = 0.f;
  for (int i = 0; i < CL; i++) {
    float nr = pr * lr - pi * li;
    float ni = pr * li + pi * lr;
    pr = nr; pi = ni;
  }
  scal[n] = lr; scal[256 + n] = li;
  scal[512 + n] = pr; scal[768 + n] = pi;
  scal[1024 + n] = g;
}

// ---------------- Weight prep ----------------
__global__ void prep_bu(const float* __restrict__ B_re, const float* __restrict__ B_im,
                        const float* __restrict__ scal, bf16* __restrict__ WB) {
  size_t i = (size_t)blockIdx.x * 256 + threadIdx.x;   // over 512*1024
  int row = (int)(i >> 10), col = (int)(i & 1023);
  int n = row >> 1;
  const float* src = (row & 1) ? B_im : B_re;
  WB[i] = (bf16)(scal[1024 + n] * src[n * 1024 + col]);
}

__global__ void prep_y(const float* __restrict__ C_re, const float* __restrict__ C_im,
                       const float* __restrict__ D_mat, bf16* __restrict__ WB) {
  size_t i = (size_t)blockIdx.x * 256 + threadIdx.x;   // over 1024*1536
  int m = (int)(i / 1536), c = (int)(i % 1536);
  float v;
  if (c < 256)       v = C_re[m * 256 + c];
  else if (c < 512)  v = -C_im[m * 256 + (c - 256)];
  else               v = D_mat[m * 1024 + (c - 512)];
  WB[i] = (bf16)v;
}

__global__ void transpose_to_bf16(const float* __restrict__ in, bf16* __restrict__ out,
                                  int R, int C) {
  __shared__ float tile[32][33];
  int c0 = blockIdx.x * 32, r0 = blockIdx.y * 32;
  int tx = threadIdx.x, ty = threadIdx.y;
  for (int i = 0; i < 32; i += 8)
    tile[ty + i][tx] = in[(size_t)(r0 + ty + i) * C + c0 + tx];
  __syncthreads();
  for (int i = 0; i < 32; i += 8)
    out[(size_t)(c0 + ty + i) * R + r0 + tx] = (bf16)tile[tx][ty + i];
}

__global__ void conv_x(const float4* __restrict__ x, bf16* __restrict__ XS) {
  size_t i = (size_t)blockIdx.x * 256 + threadIdx.x;  // float4 index
  size_t t = i >> 8;
  int d4 = (int)(i & 255);
  float4 v = x[i];
  bf16* o = XS + t * 1536 + 512 + (size_t)d4 * 4;
  o[0] = (bf16)v.x; o[1] = (bf16)v.y; o[2] = (bf16)v.z; o[3] = (bf16)v.w;
}

// ---------------- GEMM: C[m,n] = sum_k A[m,k] * Bt[n,k] ----------------
// Block tile 256(M) x 128(N), BK=32. 4 waves in 2x2; wave tile 128x64 as
// 8x4 mfma_16x16x32. XCD swizzle: XCD (bid%8) owns a contiguous slab,
// decomposed as 8-row M-groups sweeping all N.
// EPI: 0 = store bf16, 1 = gelu->bf16, 2 = out = xres + sigmoid(reslog)*acc (f32)
template <int EPI>
__global__ __launch_bounds__(256, 2) void gemm_bt(
    const bf16* __restrict__ A, int lda,
    const bf16* __restrict__ Bt, int ldb,
    void* __restrict__ C, int ldc, int K, int mt, int nt,
    const float* __restrict__ xres, const float* __restrict__ reslog) {
  __shared__ __align__(16) bf16 sA[256 * 32];   // 16 KB
  __shared__ __align__(16) bf16 sB[128 * 32];   // 8 KB
  int tid = threadIdx.x;
  int wave = tid >> 6, lane = tid & 63;
  int q = lane >> 4, l16 = lane & 15;
  int wm = (wave & 1) * 128, wn = (wave >> 1) * 64;

  // tile swizzle
  int nb = mt * nt;
  int per = nb >> 3;
  int t = (blockIdx.x & 7) * per + (blockIdx.x >> 3);
  int gsz = 8 * nt;
  int g = t / gsz, r = t % gsz;
  int tm = g * 8 + (r & 7);
  int tn = r >> 3;
  size_t m0 = (size_t)tm * 256, n0 = (size_t)tn * 128;

  f32x4 acc[8][4] = {};

  // staging: 24 chunks of 1KB (16 A + 8 B); wave handles 6
  const bf16* gp[6];
  bf16* lp[6];
#pragma unroll
  for (int cc = 0; cc < 6; cc++) {
    int c = wave * 6 + cc;
    if (c < 16) {
      int fe = (c * 64 + lane) * 8;
      gp[cc] = A + (m0 + (fe >> 5)) * (size_t)lda + (fe & 31);
      lp[cc] = &sA[fe];
    } else {
      int fe = ((c - 16) * 64 + lane) * 8;
      gp[cc] = Bt + (n0 + (fe >> 5)) * (size_t)ldb + (fe & 31);
      lp[cc] = &sB[fe];
    }
  }

  for (int k0 = 0; k0 < K; k0 += 32) {
#pragma unroll
    for (int cc = 0; cc < 6; cc++)
      async16(gp[cc] + k0, lp[cc]);
    __syncthreads();
    bf16x8 afr[8], bfr[4];
#pragma unroll
    for (int i = 0; i < 8; i++)
      afr[i] = *(const bf16x8*)&sA[(wm + i * 16 + l16) * 32 + q * 8];
#pragma unroll
    for (int i = 0; i < 4; i++)
      bfr[i] = *(const bf16x8*)&sB[(wn + i * 16 + l16) * 32 + q * 8];
#pragma unroll
    for (int mi = 0; mi < 8; mi++)
#pragma unroll
      for (int ni = 0; ni < 4; ni++)
        acc[mi][ni] = __builtin_amdgcn_mfma_f32_16x16x32_bf16(afr[mi], bfr[ni], acc[mi][ni], 0, 0, 0);
    __syncthreads();
  }

  float sig = 0.f;
  if (EPI == 2) sig = 1.f / (1.f + __expf(-reslog[0]));
#pragma unroll
  for (int mi = 0; mi < 8; mi++)
#pragma unroll
    for (int ni = 0; ni < 4; ni++) {
      size_t col = n0 + wn + ni * 16 + l16;
#pragma unroll
      for (int r2 = 0; r2 < 4; r2++) {
        size_t row = m0 + wm + mi * 16 + q * 4 + r2;
        float v = acc[mi][ni][r2];
        size_t off = row * (size_t)ldc + col;
        if (EPI == 0) {
          ((bf16*)C)[off] = (bf16)v;
        } else if (EPI == 1) {
          float z = 0.7978845608f * (v + 0.044715f * v * v * v);
          float gv = v / (1.f + __expf(-2.f * z));   // v*0.5*(1+tanh(z))
          ((bf16*)C)[off] = (bf16)gv;
        } else {
          ((float*)C)[off] = xres[off] + sig * v;
        }
      }
    }
}

// ---------------- Scan ----------------
__global__ void scan_pass1(const bf16* __restrict__ Bu, const float* __restrict__ scal,
                           float2* __restrict__ H) {
  int b = blockIdx.x >> 6, c = blockIdx.x & 63, n = threadIdx.x;
  float lr = scal[n], li = scal[256 + n];
  float sr = 0.f, si = 0.f;
  size_t t0 = (size_t)b * L_ + (size_t)c * CL;
  const uint32_t* p = (const uint32_t*)(Bu + t0 * 512) + n;
  for (int j = 0; j < CL; j++) {
    uint32_t u = p[(size_t)j * 256];
    float ur = bfbits(u & 0xffffu), ui = bfbits(u >> 16);
    float nr = lr * sr - li * si + ur;
    float ni = lr * si + li * sr + ui;
    sr = nr; si = ni;
  }
  H[(size_t)(b * NC + c) * 256 + n] = make_float2(sr, si);
}

__global__ void scan_pass2(const float2* __restrict__ H, const float* __restrict__ scal,
                           float2* __restrict__ Carry) {
  int b = blockIdx.x, n = threadIdx.x;
  float Pr = scal[512 + n], Pi = scal[768 + n];
  float cr = 0.f, ci = 0.f;
  for (int c = 0; c < NC; c++) {
    Carry[(size_t)(b * NC + c) * 256 + n] = make_float2(cr, ci);
    float2 h = H[(size_t)(b * NC + c) * 256 + n];
    float nr = Pr * cr - Pi * ci + h.x;
    float ni = Pr * ci + Pi * cr + h.y;
    cr = nr; ci = ni;
  }
}

// st layout: PLANAR-GLOBAL — st[0..1023] = re (b-major), st[1024..2047] = im
__global__ void scan_pass3(const bf16* __restrict__ Bu, const float* __restrict__ scal,
                           const float2* __restrict__ Carry, bf16* __restrict__ XS,
                           float* __restrict__ st) {
  int b = blockIdx.x >> 6, c = blockIdx.x & 63, n = threadIdx.x;
  float lr = scal[n], li = scal[256 + n];
  float2 cv = Carry[(size_t)(b * NC + c) * 256 + n];
  float sr = cv.x, si = cv.y;
  size_t t0 = (size_t)b * L_ + (size_t)c * CL;
  const uint32_t* p = (const uint32_t*)(Bu + t0 * 512) + n;
  bf16* qp = XS + t0 * 1536 + n;
  for (int j = 0; j < CL; j++) {
    uint32_t u = p[(size_t)j * 256];
    float ur = bfbits(u & 0xffffu), ui = bfbits(u >> 16);
    float nr = lr * sr - li * si + ur;
    float ni = lr * si + li * sr + ui;
    sr = nr; si = ni;
    qp[(size_t)j * 1536] = (bf16)sr;
    qp[(size_t)j * 1536 + 256] = (bf16)si;
  }
  if (c == NC - 1) {
    st[(size_t)b * 256 + n] = sr;
    st[1024 + (size_t)b * 256 + n] = si;
  }
}

// ---------------- Launch ----------------
extern "C" void kernel_launch(void* const* d_in, const int* in_sizes, int n_in,
                              void* d_out, int out_size, void* d_ws, size_t ws_size,
                              hipStream_t stream) {
  const float* x      = (const float*)d_in[0];
  const float* nu_log = (const float*)d_in[1];
  const float* th_log = (const float*)d_in[2];
  const float* B_re   = (const float*)d_in[3];
  const float* B_im   = (const float*)d_in[4];
  const float* C_re   = (const float*)d_in[5];
  const float* C_im   = (const float*)d_in[6];
  const float* D_mat  = (const float*)d_in[7];
  const float* W1     = (const float*)d_in[8];
  const float* W2     = (const float*)d_in[9];
  const float* reslog = (const float*)d_in[10];

  char* wsb = (char*)d_ws;
  size_t off = 0;
  auto alloc = [&](size_t bytes) {
    void* p = wsb + off;
    off += (bytes + 255) & ~(size_t)255;
    return p;
  };
  float*  scal = (float*)alloc(5 * 256 * 4);
  bf16*   WBbu = (bf16*)alloc((size_t)512 * 1024 * 2);
  bf16*   WBy  = (bf16*)alloc((size_t)1024 * 1536 * 2);
  bf16*   WB1  = (bf16*)alloc((size_t)4096 * 1024 * 2);   // W1^T
  bf16*   WB2  = (bf16*)alloc((size_t)1024 * 4096 * 2);   // W2^T
  float2* H    = (float2*)alloc((size_t)B_ * NC * 256 * 8);
  float2* Cr   = (float2*)alloc((size_t)B_ * NC * 256 * 8);
  bf16*   Ybf  = (bf16*)alloc((size_t)BL * 1024 * 2);
  bf16*   XS   = (bf16*)alloc((size_t)BL * 1536 * 2);     // [Sr|Si|x]
  bf16*   Bu   = (bf16*)alloc((size_t)BL * 512 * 2);
  // gelu buffer (8192x4096 bf16 = 64 MB) aliases XS+Bu (dead by MLP time)
  bf16*   Hbf  = XS;

  float* out = (float*)d_out;
  float* st  = out + (size_t)BL * DM;

  phaseA<<<1, 256, 0, stream>>>(nu_log, th_log, scal);
  prep_bu<<<512 * 1024 / 256, 256, 0, stream>>>(B_re, B_im, scal, WBbu);
  prep_y<<<1024 * 1536 / 256, 256, 0, stream>>>(C_re, C_im, D_mat, WBy);
  transpose_to_bf16<<<dim3(4096 / 32, 1024 / 32), dim3(32, 8), 0, stream>>>(W1, WB1, 1024, 4096);
  transpose_to_bf16<<<dim3(1024 / 32, 4096 / 32), dim3(32, 8), 0, stream>>>(W2, WB2, 4096, 1024);
  conv_x<<<BL * 256 / 256, 256, 0, stream>>>((const float4*)x, XS);

  // Bu = x @ [gammaB]^T  (M=16384, N=512, K=1024): 64x4 tiles of 256x128
  gemm_bt<0><<<64 * 4, 256, 0, stream>>>(
      XS + 512, 1536, WBbu, 1024, Bu, 512, 1024, 64, 4, nullptr, nullptr);

  scan_pass1<<<B_ * NC, 256, 0, stream>>>(Bu, scal, H);
  scan_pass2<<<B_, 256, 0, stream>>>(H, scal, Cr);
  scan_pass3<<<B_ * NC, 256, 0, stream>>>(Bu, scal, Cr, XS, st);

  // y = [Sr|Si|x] @ [C_re|-C_im|D]^T  (M=16384, N=1024, K=1536): 64x8 tiles
  gemm_bt<0><<<64 * 8, 256, 0, stream>>>(
      XS, 1536, WBy, 1536, Ybf, 1024, 1536, 64, 8, nullptr, nullptr);

  // MLP, M-chunked by 8192 rows (2 chunks)
  for (int i = 0; i < 2; i++) {
    const bf16* Yc = Ybf + (size_t)i * 8192 * 1024;
    float* Oc = out + (size_t)i * 8192 * 1024;
    const float* Xc = x + (size_t)i * 8192 * 1024;
    gemm_bt<1><<<32 * 32, 256, 0, stream>>>(
        Yc, 1024, WB1, 1024, Hbf, 4096, 1024, 32, 32, nullptr, nullptr);
    gemm_bt<2><<<32 * 8, 256, 0, stream>>>(
        Hbf, 4096, WB2, 4096, Oc, 1024, 4096, 32, 8, Xc, reslog);
  }
}

// Round 5
// 604.243 us; speedup vs baseline: 1.1919x; 1.1919x over previous
//
#include <hip/hip_runtime.h>
#include <stdint.h>

typedef __bf16 bf16;
typedef bf16 bf16x8 __attribute__((ext_vector_type(8)));
typedef float f32x4 __attribute__((ext_vector_type(4)));

#define B_  4
#define L_  4096
#define DM  1024
#define DS  256
#define DH  4096
#define BL  16384   // B_*L_
#define CL  64      // scan chunk length
#define NC  64      // chunks per sequence

__device__ __forceinline__ float bfbits(uint32_t lo16) {
  union { uint32_t u; float f; } v; v.u = lo16 << 16; return v.f;
}

__device__ __forceinline__ void async16(const bf16* g, bf16* l) {
  __builtin_amdgcn_global_load_lds(
      (const __attribute__((address_space(1))) uint32_t*)g,
      (__attribute__((address_space(3))) uint32_t*)l, 16, 0, 0);
}

// ---------------- Phase A ----------------
__global__ void phaseA(const float* __restrict__ nu_log,
                       const float* __restrict__ th_log,
                       float* __restrict__ scal) {
  int n = threadIdx.x;
  float nu = __expf(nu_log[n]);
  float th = __expf(th_log[n]);
  float mod = __expf(-nu);
  float lr = mod * cosf(th);
  float li = mod * sinf(th);
  float g = sqrtf(fmaxf(1.0f - mod * mod, 0.0f));
  float pr = 1.f, pi = 0.f;
  for (int i = 0; i < CL; i++) {
    float nr = pr * lr - pi * li;
    float ni = pr * li + pi * lr;
    pr = nr; pi = ni;
  }
  scal[n] = lr; scal[256 + n] = li;
  scal[512 + n] = pr; scal[768 + n] = pi;
  scal[1024 + n] = g;
}

// ---------------- Weight prep ----------------
__global__ void prep_bu(const float* __restrict__ B_re, const float* __restrict__ B_im,
                        const float* __restrict__ scal, bf16* __restrict__ WB) {
  size_t i = (size_t)blockIdx.x * 256 + threadIdx.x;   // over 512*1024
  int row = (int)(i >> 10), col = (int)(i & 1023);
  int n = row >> 1;
  const float* src = (row & 1) ? B_im : B_re;
  WB[i] = (bf16)(scal[1024 + n] * src[n * 1024 + col]);
}

__global__ void prep_y(const float* __restrict__ C_re, const float* __restrict__ C_im,
                       const float* __restrict__ D_mat, bf16* __restrict__ WB) {
  size_t i = (size_t)blockIdx.x * 256 + threadIdx.x;   // over 1024*1536
  int m = (int)(i / 1536), c = (int)(i % 1536);
  float v;
  if (c < 256)       v = C_re[m * 256 + c];
  else if (c < 512)  v = -C_im[m * 256 + (c - 256)];
  else               v = D_mat[m * 1024 + (c - 512)];
  WB[i] = (bf16)v;
}

__global__ void transpose_to_bf16(const float* __restrict__ in, bf16* __restrict__ out,
                                  int R, int C) {
  __shared__ float tile[32][33];
  int c0 = blockIdx.x * 32, r0 = blockIdx.y * 32;
  int tx = threadIdx.x, ty = threadIdx.y;
  for (int i = 0; i < 32; i += 8)
    tile[ty + i][tx] = in[(size_t)(r0 + ty + i) * C + c0 + tx];
  __syncthreads();
  for (int i = 0; i < 32; i += 8)
    out[(size_t)(c0 + ty + i) * R + r0 + tx] = (bf16)tile[tx][ty + i];
}

__global__ void conv_x(const float4* __restrict__ x, bf16* __restrict__ XS) {
  size_t i = (size_t)blockIdx.x * 256 + threadIdx.x;  // float4 index
  size_t t = i >> 8;
  int d4 = (int)(i & 255);
  float4 v = x[i];
  bf16* o = XS + t * 1536 + 512 + (size_t)d4 * 4;
  o[0] = (bf16)v.x; o[1] = (bf16)v.y; o[2] = (bf16)v.z; o[3] = (bf16)v.w;
}

// ---------------- GEMM: C[m,n] = sum_k A[m,k] * Bt[n,k] ----------------
// 128x128 block tile, BK=32, 4 waves 2x2, wave tile 64x64 (4x4 mfma 16x16x32).
// 3-stage LDS pipeline, 2-deep global_load_lds prefetch, raw s_barrier +
// s_waitcnt vmcnt(4) (only final iter drains to 0). XCD-aware tile swizzle.
// EPI: 0 = store bf16, 1 = gelu->bf16, 2 = out = xres + sigmoid(reslog)*acc (f32)
template <int EPI>
__global__ __launch_bounds__(256, 3) void gemm_bt(
    const bf16* __restrict__ A, int lda,
    const bf16* __restrict__ Bt, int ldb,
    void* __restrict__ C, int ldc, int K, int mt, int nt,
    const float* __restrict__ xres, const float* __restrict__ reslog) {
  __shared__ __align__(16) bf16 sAb[3 * 128 * 32];   // 24 KB
  __shared__ __align__(16) bf16 sBb[3 * 128 * 32];   // 24 KB
  int tid = threadIdx.x;
  int wave = tid >> 6, lane = tid & 63;
  int q = lane >> 4, l16 = lane & 15;
  int wm = (wave & 1) * 64, wn = (wave >> 1) * 64;

  // XCD tile swizzle
  int nb = mt * nt;
  int per = nb >> 3;
  int t = (blockIdx.x & 7) * per + (blockIdx.x >> 3);
  int gsz = 8 * nt;
  int g = t / gsz, r = t % gsz;
  int tm = g * 8 + (r & 7);
  int tn = r >> 3;
  size_t m0 = (size_t)tm * 128, n0 = (size_t)tn * 128;

  f32x4 acc[4][4] = {};

  // staging: per wave 2 A-chunks + 2 B-chunks (1 KB each). fe in [0,4096).
  int stg_fe[2];
  const bf16* gpA[2];
  const bf16* gpB[2];
#pragma unroll
  for (int cc = 0; cc < 2; cc++) {
    int chunk = wave * 2 + cc;
    int fe = (chunk * 64 + lane) * 8;
    stg_fe[cc] = fe;
    gpA[cc] = A + (m0 + (fe >> 5)) * (size_t)lda + (fe & 31);
    gpB[cc] = Bt + (n0 + (fe >> 5)) * (size_t)ldb + (fe & 31);
  }

  int NI = K >> 5;
  // prologue: batches 0 and 1
#pragma unroll
  for (int b = 0; b < 2; b++)
#pragma unroll
    for (int cc = 0; cc < 2; cc++) {
      async16(gpA[cc] + b * 32, &sAb[b * 4096 + stg_fe[cc]]);
      async16(gpB[cc] + b * 32, &sBb[b * 4096 + stg_fe[cc]]);
    }

  int p = 0, p2 = 2;
  for (int i = 0; i < NI; i++) {
    if (i + 1 < NI) __builtin_amdgcn_s_waitcnt(0x0F74);  // vmcnt(4): batch i landed
    else            __builtin_amdgcn_s_waitcnt(0x0F70);  // vmcnt(0): last batch
    __builtin_amdgcn_s_barrier();
    asm volatile("" ::: "memory");   // keep LDS reads below the barrier

    const bf16* a_base = &sAb[p * 4096];
    const bf16* b_base = &sBb[p * 4096];
    bf16x8 afr[4], bfr[4];
#pragma unroll
    for (int i4 = 0; i4 < 4; i4++)
      afr[i4] = *(const bf16x8*)&a_base[(wm + i4 * 16 + l16) * 32 + q * 8];
#pragma unroll
    for (int i4 = 0; i4 < 4; i4++)
      bfr[i4] = *(const bf16x8*)&b_base[(wn + i4 * 16 + l16) * 32 + q * 8];

    if (i + 2 < NI) {
      int k2 = (i + 2) * 32;
#pragma unroll
      for (int cc = 0; cc < 2; cc++) {
        async16(gpA[cc] + k2, &sAb[p2 * 4096 + stg_fe[cc]]);
        async16(gpB[cc] + k2, &sBb[p2 * 4096 + stg_fe[cc]]);
      }
    }

#pragma unroll
    for (int mi = 0; mi < 4; mi++)
#pragma unroll
      for (int ni = 0; ni < 4; ni++)
        acc[mi][ni] = __builtin_amdgcn_mfma_f32_16x16x32_bf16(afr[mi], bfr[ni], acc[mi][ni], 0, 0, 0);

    p = (p == 2) ? 0 : p + 1;
    p2 = (p2 == 2) ? 0 : p2 + 1;
  }

  float sig = 0.f;
  if (EPI == 2) sig = 1.f / (1.f + __expf(-reslog[0]));
#pragma unroll
  for (int mi = 0; mi < 4; mi++)
#pragma unroll
    for (int ni = 0; ni < 4; ni++) {
      size_t col = n0 + wn + ni * 16 + l16;
#pragma unroll
      for (int r2 = 0; r2 < 4; r2++) {
        size_t row = m0 + wm + mi * 16 + q * 4 + r2;
        float v = acc[mi][ni][r2];
        size_t off = row * (size_t)ldc + col;
        if (EPI == 0) {
          ((bf16*)C)[off] = (bf16)v;
        } else if (EPI == 1) {
          float z = 0.7978845608f * (v + 0.044715f * v * v * v);
          float gv = v / (1.f + __expf(-2.f * z));   // v*0.5*(1+tanh(z))
          ((bf16*)C)[off] = (bf16)gv;
        } else {
          ((float*)C)[off] = xres[off] + sig * v;
        }
      }
    }
}

// ---------------- Scan ----------------
__global__ void scan_pass1(const bf16* __restrict__ Bu, const float* __restrict__ scal,
                           float2* __restrict__ H) {
  int b = blockIdx.x >> 6, c = blockIdx.x & 63, n = threadIdx.x;
  float lr = scal[n], li = scal[256 + n];
  float sr = 0.f, si = 0.f;
  size_t t0 = (size_t)b * L_ + (size_t)c * CL;
  const uint32_t* p = (const uint32_t*)(Bu + t0 * 512) + n;
  for (int j = 0; j < CL; j++) {
    uint32_t u = p[(size_t)j * 256];
    float ur = bfbits(u & 0xffffu), ui = bfbits(u >> 16);
    float nr = lr * sr - li * si + ur;
    float ni = lr * si + li * sr + ui;
    sr = nr; si = ni;
  }
  H[(size_t)(b * NC + c) * 256 + n] = make_float2(sr, si);
}

__global__ void scan_pass2(const float2* __restrict__ H, const float* __restrict__ scal,
                           float2* __restrict__ Carry) {
  int b = blockIdx.x, n = threadIdx.x;
  float Pr = scal[512 + n], Pi = scal[768 + n];
  float cr = 0.f, ci = 0.f;
  for (int c = 0; c < NC; c++) {
    Carry[(size_t)(b * NC + c) * 256 + n] = make_float2(cr, ci);
    float2 h = H[(size_t)(b * NC + c) * 256 + n];
    float nr = Pr * cr - Pi * ci + h.x;
    float ni = Pr * ci + Pi * cr + h.y;
    cr = nr; ci = ni;
  }
}

// st layout: PLANAR-GLOBAL — st[0..1023] = re (b-major), st[1024..2047] = im
__global__ void scan_pass3(const bf16* __restrict__ Bu, const float* __restrict__ scal,
                           const float2* __restrict__ Carry, bf16* __restrict__ XS,
                           float* __restrict__ st) {
  int b = blockIdx.x >> 6, c = blockIdx.x & 63, n = threadIdx.x;
  float lr = scal[n], li = scal[256 + n];
  float2 cv = Carry[(size_t)(b * NC + c) * 256 + n];
  float sr = cv.x, si = cv.y;
  size_t t0 = (size_t)b * L_ + (size_t)c * CL;
  const uint32_t* p = (const uint32_t*)(Bu + t0 * 512) + n;
  bf16* qp = XS + t0 * 1536 + n;
  for (int j = 0; j < CL; j++) {
    uint32_t u = p[(size_t)j * 256];
    float ur = bfbits(u & 0xffffu), ui = bfbits(u >> 16);
    float nr = lr * sr - li * si + ur;
    float ni = lr * si + li * sr + ui;
    sr = nr; si = ni;
    qp[(size_t)j * 1536] = (bf16)sr;
    qp[(size_t)j * 1536 + 256] = (bf16)si;
  }
  if (c == NC - 1) {
    st[(size_t)b * 256 + n] = sr;
    st[1024 + (size_t)b * 256 + n] = si;
  }
}

// ---------------- Launch ----------------
extern "C" void kernel_launch(void* const* d_in, const int* in_sizes, int n_in,
                              void* d_out, int out_size, void* d_ws, size_t ws_size,
                              hipStream_t stream) {
  const float* x      = (const float*)d_in[0];
  const float* nu_log = (const float*)d_in[1];
  const float* th_log = (const float*)d_in[2];
  const float* B_re   = (const float*)d_in[3];
  const float* B_im   = (const float*)d_in[4];
  const float* C_re   = (const float*)d_in[5];
  const float* C_im   = (const float*)d_in[6];
  const float* D_mat  = (const float*)d_in[7];
  const float* W1     = (const float*)d_in[8];
  const float* W2     = (const float*)d_in[9];
  const float* reslog = (const float*)d_in[10];

  char* wsb = (char*)d_ws;
  size_t off = 0;
  auto alloc = [&](size_t bytes) {
    void* p = wsb + off;
    off += (bytes + 255) & ~(size_t)255;
    return p;
  };
  float*  scal = (float*)alloc(5 * 256 * 4);
  bf16*   WBbu = (bf16*)alloc((size_t)512 * 1024 * 2);
  bf16*   WBy  = (bf16*)alloc((size_t)1024 * 1536 * 2);
  bf16*   WB1  = (bf16*)alloc((size_t)4096 * 1024 * 2);   // W1^T
  bf16*   WB2  = (bf16*)alloc((size_t)1024 * 4096 * 2);   // W2^T
  float2* H    = (float2*)alloc((size_t)B_ * NC * 256 * 8);
  float2* Cr   = (float2*)alloc((size_t)B_ * NC * 256 * 8);
  bf16*   Ybf  = (bf16*)alloc((size_t)BL * 1024 * 2);
  bf16*   XS   = (bf16*)alloc((size_t)BL * 1536 * 2);     // [Sr|Si|x]
  bf16*   Bu   = (bf16*)alloc((size_t)BL * 512 * 2);
  // gelu buffer (8192x4096 bf16 = 64 MB) aliases XS+Bu (dead by MLP time)
  bf16*   Hbf  = XS;

  float* out = (float*)d_out;
  float* st  = out + (size_t)BL * DM;

  phaseA<<<1, 256, 0, stream>>>(nu_log, th_log, scal);
  prep_bu<<<512 * 1024 / 256, 256, 0, stream>>>(B_re, B_im, scal, WBbu);
  prep_y<<<1024 * 1536 / 256, 256, 0, stream>>>(C_re, C_im, D_mat, WBy);
  transpose_to_bf16<<<dim3(4096 / 32, 1024 / 32), dim3(32, 8), 0, stream>>>(W1, WB1, 1024, 4096);
  transpose_to_bf16<<<dim3(1024 / 32, 4096 / 32), dim3(32, 8), 0, stream>>>(W2, WB2, 4096, 1024);
  conv_x<<<BL * 256 / 256, 256, 0, stream>>>((const float4*)x, XS);

  // Bu = x @ [gammaB]^T  (M=16384, N=512, K=1024): 128x4 tiles
  gemm_bt<0><<<128 * 4, 256, 0, stream>>>(
      XS + 512, 1536, WBbu, 1024, Bu, 512, 1024, 128, 4, nullptr, nullptr);

  scan_pass1<<<B_ * NC, 256, 0, stream>>>(Bu, scal, H);
  scan_pass2<<<B_, 256, 0, stream>>>(H, scal, Cr);
  scan_pass3<<<B_ * NC, 256, 0, stream>>>(Bu, scal, Cr, XS, st);

  // y = [Sr|Si|x] @ [C_re|-C_im|D]^T  (M=16384, N=1024, K=1536): 128x8 tiles
  gemm_bt<0><<<128 * 8, 256, 0, stream>>>(
      XS, 1536, WBy, 1536, Ybf, 1024, 1536, 128, 8, nullptr, nullptr);

  // MLP, M-chunked by 8192 rows (2 chunks)
  for (int i = 0; i < 2; i++) {
    const bf16* Yc = Ybf + (size_t)i * 8192 * 1024;
    float* Oc = out + (size_t)i * 8192 * 1024;
    const float* Xc = x + (size_t)i * 8192 * 1024;
    gemm_bt<1><<<64 * 32, 256, 0, stream>>>(
        Yc, 1024, WB1, 1024, Hbf, 4096, 1024, 64, 32, nullptr, nullptr);
    gemm_bt<2><<<64 * 8, 256, 0, stream>>>(
        Hbf, 4096, WB2, 4096, Oc, 1024, 4096, 64, 8, Xc, reslog);
  }
}